// Round 13
// baseline (110.962 us; speedup 1.0000x reference)
//
#include <hip/hip_runtime.h>
#include <hip/hip_bf16.h>
#include <math.h>

#define IN_DIM 256
#define OUT_DIM 64
#define CHUNK_LOG2 12          // 4096 edges per chunk
#define BK_LOG2 7              // 128 dsts per coarse bucket
#define MAXNB 512              // max coarse buckets (n_p <= 65536)
#define BCAP 6144              // fixed bucket capacity (mean 4096, sd 64 -> 32 sigma)

typedef __attribute__((ext_vector_type(8))) short short8v;   // 8 bf16 (4 VGPRs)
typedef __attribute__((ext_vector_type(4))) float f32x4;     // MFMA acc

__device__ __forceinline__ unsigned short f2bf(float f) {
    unsigned u = __float_as_uint(f);
    unsigned r = (u + 0x7fffu + ((u >> 16) & 1u)) >> 16;     // RTNE
    return (unsigned short)r;
}

__device__ __forceinline__ float bf2f(unsigned short b) {
    return __uint_as_float(((unsigned)b) << 16);
}

__device__ __forceinline__ float edge_score(float x) {
    float e = x > 0.0f ? x : 0.01f * x;   // leaky_relu, slope 0.01
    if (e == 0.0f) e = -1000.0f;          // where(e==0, -1000, e)
    return e;
}

// Pre-pack W_fc (256x64 f32) into MFMA B-fragments, bf16. Grid: 8 x 256.
__global__ __launch_bounds__(256) void prep_kernel(
    const float* __restrict__ Wfc, short8v* __restrict__ wtf)
{
    const int v = blockIdx.x * 256 + threadIdx.x;   // 0..2047
    const int ks = v >> 8;
    const int t = (v >> 6) & 3;
    const int lane = v & 63;
    const int lg = lane >> 4, lr = lane & 15;
    short8v b;
    #pragma unroll
    for (int j = 0; j < 8; ++j) {
        const int k = ks * 32 + lg * 8 + j;
        b[j] = (short)f2bf(Wfc[k * OUT_DIM + t * 16 + lr]);
    }
    wtf[v] = b;
}

// z = h @ W_fc via MFMA. h staged as bf16 in 32 KB LDS (reg-convert, XOR-swz);
// B processed in two 32-dim halves (64 regs instead of 128). Fused tail:
// blocks 0..nchunks-1 scatter their 4096-edge chunk into fixed-capacity
// dst-bucket regions.
__global__ __launch_bounds__(256, 3) void gemm_s_kernel(
    const float* __restrict__ h, const short8v* __restrict__ wtf,
    const float* __restrict__ Wattn, const int* __restrict__ esrc,
    const int* __restrict__ edst, unsigned short* __restrict__ z,
    float* __restrict__ s, int* __restrict__ bres, int* __restrict__ brec,
    int n_rows, int n_edges, int nb)
{
    __shared__ short hl2[64 * 256];   // 32 KB bf16 tile; reused as scatter tables
    const int tid = threadIdx.x;
    const int lane = tid & 63;
    const int wv = tid >> 6;
    const int lg = lane >> 4;
    const int lr = lane & 15;
    const int row0 = blockIdx.x * 64;

    // hoist scatter chunk loads (overlap with staging)
    const int nchunks = (n_edges + (1 << CHUNK_LOG2) - 1) >> CHUNK_LOG2;
    const bool hasChunk = blockIdx.x < nchunks;
    const bool fullChunk = hasChunk &&
        ((blockIdx.x << CHUNK_LOG2) + (1 << CHUNK_LOG2) <= n_edges);
    int4 ed[4], es[4];
    if (fullChunk) {
        const int4* ep = (const int4*)edst + (blockIdx.x << (CHUNK_LOG2 - 2));
        const int4* sp = (const int4*)esrc + (blockIdx.x << (CHUNK_LOG2 - 2));
        #pragma unroll
        for (int j = 0; j < 4; ++j) { ed[j] = ep[j * 256 + tid]; es[j] = sp[j * 256 + tid]; }
    }

    float a_attn[4];
    #pragma unroll
    for (int t = 0; t < 4; ++t) a_attn[t] = Wattn[t * 16 + lr];

    // stage h tile as bf16: 8 slot-tasks/thread; slot s' = s ^ (r&31)
    #pragma unroll
    for (int i = 0; i < 8; ++i) {
        const int q = i * 256 + tid;        // 0..2047
        const int r = q >> 5;               // tile row 0..63
        const int sl = q & 31;              // 16B bf16 slot within row
        const int grow = min(row0 + r, n_rows - 1);
        const float4* hp = (const float4*)(h + (size_t)grow * IN_DIM + sl * 8);
        const float4 xa = hp[0];
        const float4 xb = hp[1];
        union { short8v v; __hip_bfloat162 h2[4]; } u;
        u.h2[0] = __float22bfloat162_rn(float2{xa.x, xa.y});
        u.h2[1] = __float22bfloat162_rn(float2{xa.z, xa.w});
        u.h2[2] = __float22bfloat162_rn(float2{xb.x, xb.y});
        u.h2[3] = __float22bfloat162_rn(float2{xb.z, xb.w});
        *(short8v*)((char*)hl2 + r * 512 + ((sl ^ (r & 31)) << 4)) = u.v;
    }
    __syncthreads();

    const int rA = wv * 16 + lr;
    const char* rbase = (const char*)hl2 + rA * 512;
    const int rsw = rA & 31;

    float svj[4] = {0.f, 0.f, 0.f, 0.f};

    #pragma unroll
    for (int hf = 0; hf < 2; ++hf) {
        short8v Bf[8][2];
        #pragma unroll
        for (int ks = 0; ks < 8; ++ks)
            #pragma unroll
            for (int tt = 0; tt < 2; ++tt)
                Bf[ks][tt] = wtf[(ks * 4 + hf * 2 + tt) * 64 + lane];

        f32x4 acc[2];
        acc[0] = (f32x4){0.f, 0.f, 0.f, 0.f};
        acc[1] = (f32x4){0.f, 0.f, 0.f, 0.f};

        #pragma unroll
        for (int ks = 0; ks < 8; ++ks) {
            const short8v av =
                *(const short8v*)(rbase + (((ks * 4 + lg) ^ rsw) << 4));
            acc[0] = __builtin_amdgcn_mfma_f32_16x16x32_bf16(av, Bf[ks][0], acc[0], 0, 0, 0);
            acc[1] = __builtin_amdgcn_mfma_f32_16x16x32_bf16(av, Bf[ks][1], acc[1], 0, 0, 0);
        }

        // half epilogue: C/D layout col = lane&15, row = wv*16 + lg*4 + j
        #pragma unroll
        for (int j = 0; j < 4; ++j) {
            const int row = row0 + wv * 16 + lg * 4 + j;
            const bool ok = row < n_rows;
            #pragma unroll
            for (int tt = 0; tt < 2; ++tt) {
                const int t = hf * 2 + tt;
                const float v = acc[tt][j];
                if (ok) z[(size_t)row * OUT_DIM + t * 16 + lr] =
                    __bfloat16_as_ushort(__float2bfloat16(v));
                svj[j] = fmaf(v, a_attn[t], svj[j]);
            }
        }
    }

    #pragma unroll
    for (int j = 0; j < 4; ++j) {
        const int row = row0 + wv * 16 + lg * 4 + j;
        float p = svj[j];
        #pragma unroll
        for (int o = 1; o < 16; o <<= 1) p += __shfl_xor(p, o);
        if (row < n_rows && lr == 0) s[row] = p;
    }

    // fused scatter into fixed-capacity bucket regions (reuse hl2)
    __syncthreads();
    int* lcnt = (int*)hl2;
    int* lwoff = lcnt + MAXNB;
    if (hasChunk) {
        for (int j2 = tid; j2 < nb; j2 += 256) lcnt[j2] = 0;
        __syncthreads();
        if (fullChunk) {
            #pragma unroll
            for (int j2 = 0; j2 < 4; ++j2) {
                atomicAdd(&lcnt[ed[j2].x >> BK_LOG2], 1);
                atomicAdd(&lcnt[ed[j2].y >> BK_LOG2], 1);
                atomicAdd(&lcnt[ed[j2].z >> BK_LOG2], 1);
                atomicAdd(&lcnt[ed[j2].w >> BK_LOG2], 1);
            }
        } else {
            const int i0 = blockIdx.x << CHUNK_LOG2;
            const int i1 = min(i0 + (1 << CHUNK_LOG2), n_edges);
            for (int i = i0 + tid; i < i1; i += 256)
                atomicAdd(&lcnt[edst[i] >> BK_LOG2], 1);
        }
        __syncthreads();
        for (int j2 = tid; j2 < nb; j2 += 256) {
            const int cv = lcnt[j2];
            lwoff[j2] = cv ? (j2 * BCAP + atomicAdd(bres + j2, cv)) : 0;
        }
        __syncthreads();
        if (fullChunk) {
            #pragma unroll
            for (int j2 = 0; j2 < 4; ++j2) {
                #define EMIT(dd, ss) { \
                    const int pos = atomicAdd(&lwoff[(dd) >> BK_LOG2], 1); \
                    brec[pos] = (ss) | (((dd) & ((1 << BK_LOG2) - 1)) << 17); }
                EMIT(ed[j2].x, es[j2].x)
                EMIT(ed[j2].y, es[j2].y)
                EMIT(ed[j2].z, es[j2].z)
                EMIT(ed[j2].w, es[j2].w)
                #undef EMIT
            }
        } else {
            const int i0 = blockIdx.x << CHUNK_LOG2;
            const int i1 = min(i0 + (1 << CHUNK_LOG2), n_edges);
            for (int i = i0 + tid; i < i1; i += 256) {
                const int d = edst[i];
                const int pos = atomicAdd(&lwoff[d >> BK_LOG2], 1);
                brec[pos] = esrc[i] | ((d & ((1 << BK_LOG2) - 1)) << 17);
            }
        }
    }
}

// per-bucket fine sort, in place: stage bucket in LDS, 128-bin count+scan,
// scatter back sorted; write (start,len) per dst.
__global__ __launch_bounds__(256) void p2_kernel(
    const int* __restrict__ bres, int* __restrict__ brec,
    int2* __restrict__ oln, int n_pnodes)
{
    __shared__ int srec[BCAP];          // 24 KB
    __shared__ int lh[128], lsc[128], lwf[128];
    const int b = blockIdx.x;
    const int tid = threadIdx.x;
    const int base = b * BCAP;
    const int len = min(bres[b], BCAP);

    if (tid < 128) lh[tid] = 0;
    __syncthreads();
    for (int i = tid; i < len; i += 256) {
        const int r = brec[base + i];
        srec[i] = r;
        atomicAdd(&lh[r >> 17], 1);
    }
    __syncthreads();
    if (tid < 128) lsc[tid] = lh[tid];
    __syncthreads();
    for (int d = 1; d < 128; d <<= 1) {
        int v = 0;
        if (tid < 128 && tid >= d) v = lsc[tid - d];
        __syncthreads();
        if (tid < 128) lsc[tid] += v;
        __syncthreads();
    }
    const int d0 = b << BK_LOG2;
    if (tid < 128) {
        const int st = lsc[tid] - lh[tid];   // exclusive within bucket
        lwf[tid] = st;
        if (d0 + tid < n_pnodes)
            oln[d0 + tid] = make_int2(base + st, lh[tid]);
    }
    __syncthreads();
    for (int i = tid; i < len; i += 256) {
        const int r = srec[i];
        const int pos = atomicAdd(&lwf[r >> 17], 1);
        brec[base + pos] = r & 0x1FFFF;      // in place: all reads staged
    }
}

// one wave per pnode: softmax + weighted z-sum over its sorted segment
__global__ __launch_bounds__(256) void segment_kernel(
    const int2* __restrict__ oln, const int* __restrict__ ssrc,
    const float* __restrict__ s, const unsigned short* __restrict__ z,
    float* __restrict__ out, int n_pnodes)
{
    const int p = blockIdx.x * 4 + (threadIdx.x >> 6);
    if (p >= n_pnodes) return;
    const int lane = threadIdx.x & 63;
    const int2 ol = oln[p];
    const int beg = ol.x;
    const int len = ol.y;
    const int end = beg + len;

    if (len == 0) {
        out[(size_t)p * OUT_DIM + lane] = 0.0f;
        return;
    }

    float acc = 0.0f, dsum = 0.0f;

    #define GATH1(tt, wsrc, ssrcv) { \
        float wt = __shfl(wsrc, tt); \
        int st = __shfl(ssrcv, tt); \
        acc = fmaf(wt, bf2f(z[(size_t)st * OUT_DIM + lane]), acc); }
    #define GATH8(tt, wsrc, ssrcv) { \
        float w0 = __shfl(wsrc, tt),     w1 = __shfl(wsrc, tt + 1); \
        float w2 = __shfl(wsrc, tt + 2), w3 = __shfl(wsrc, tt + 3); \
        float w4 = __shfl(wsrc, tt + 4), w5 = __shfl(wsrc, tt + 5); \
        float w6 = __shfl(wsrc, tt + 6), w7 = __shfl(wsrc, tt + 7); \
        int a0 = __shfl(ssrcv, tt),     a1 = __shfl(ssrcv, tt + 1); \
        int a2 = __shfl(ssrcv, tt + 2), a3 = __shfl(ssrcv, tt + 3); \
        int a4 = __shfl(ssrcv, tt + 4), a5 = __shfl(ssrcv, tt + 5); \
        int a6 = __shfl(ssrcv, tt + 6), a7 = __shfl(ssrcv, tt + 7); \
        float z0 = bf2f(z[(size_t)a0 * OUT_DIM + lane]); \
        float z1 = bf2f(z[(size_t)a1 * OUT_DIM + lane]); \
        float z2 = bf2f(z[(size_t)a2 * OUT_DIM + lane]); \
        float z3 = bf2f(z[(size_t)a3 * OUT_DIM + lane]); \
        float z4 = bf2f(z[(size_t)a4 * OUT_DIM + lane]); \
        float z5 = bf2f(z[(size_t)a5 * OUT_DIM + lane]); \
        float z6 = bf2f(z[(size_t)a6 * OUT_DIM + lane]); \
        float z7 = bf2f(z[(size_t)a7 * OUT_DIM + lane]); \
        acc = fmaf(w0, z0, acc); acc = fmaf(w1, z1, acc); \
        acc = fmaf(w2, z2, acc); acc = fmaf(w3, z3, acc); \
        acc = fmaf(w4, z4, acc); acc = fmaf(w5, z5, acc); \
        acc = fmaf(w6, z6, acc); acc = fmaf(w7, z7, acc); }

    if (len <= 64) {
        const bool v = lane < len;
        const int j = beg + (v ? lane : 0);
        const int sr = ssrc[j];
        const float e = v ? edge_score(s[sr]) : -INFINITY;
        float m = e;
        #pragma unroll
        for (int o = 32; o > 0; o >>= 1) m = fmaxf(m, __shfl_xor(m, o));
        float w = v ? __expf(e - m) : 0.0f;
        dsum = w;
        #pragma unroll
        for (int o = 32; o > 0; o >>= 1) dsum += __shfl_xor(dsum, o);

        int t = 0;
        for (; t + 8 <= len; t += 8) GATH8(t, w, sr)
        for (; t < len; ++t) GATH1(t, w, sr)
    } else {
        float m = -INFINITY;
        for (int j = beg + lane; j < end; j += 64)
            m = fmaxf(m, edge_score(s[ssrc[j]]));
        #pragma unroll
        for (int o = 32; o > 0; o >>= 1) m = fmaxf(m, __shfl_xor(m, o));

        for (int c = beg; c < end; c += 64) {
            const int j = c + lane;
            float w = 0.0f;
            int sr = 0;
            if (j < end) {
                sr = ssrc[j];
                w = __expf(edge_score(s[sr]) - m);
            }
            dsum += w;
            const int cn = min(64, end - c);
            int t = 0;
            for (; t + 8 <= cn; t += 8) GATH8(t, w, sr)
            for (; t < cn; ++t) GATH1(t, w, sr)
        }
        #pragma unroll
        for (int o = 32; o > 0; o >>= 1) dsum += __shfl_xor(dsum, o);
    }
    #undef GATH8
    #undef GATH1

    out[(size_t)p * OUT_DIM + lane] = acc / fmaxf(dsum, 1e-20f);
}

extern "C" void kernel_launch(void* const* d_in, const int* in_sizes, int n_in,
                              void* d_out, int out_size, void* d_ws, size_t ws_size,
                              hipStream_t stream)
{
    const float* h     = (const float*)d_in[0];
    const int*   esrc  = (const int*)d_in[1];
    const int*   edst  = (const int*)d_in[2];
    const float* Wfc   = (const float*)d_in[4];
    const float* Wattn = (const float*)d_in[5];
    float* out = (float*)d_out;

    const int n_w = in_sizes[0] / IN_DIM;   // 100000
    const int n_e = in_sizes[1];            // 1600000
    const int n_p = out_size / OUT_DIM;     // 50000
    const int nb  = (n_p + (1 << BK_LOG2) - 1) >> BK_LOG2;   // 391 coarse buckets

    // workspace layout (wtf first: 16B aligned)
    short8v* wtf            = (short8v*)d_ws;                          // 2048 frags (32 KB)
    unsigned short* z       = (unsigned short*)(wtf + 2048);           // n_w*64 bf16 bits
    float* s                = (float*)(z + (size_t)n_w * OUT_DIM);     // n_w
    int* brec               = (int*)(s + n_w);                         // nb * BCAP (padded buckets)
    int2* oln               = (int2*)(brec + (size_t)nb * BCAP);       // n_p (start,len)
    int* bres               = (int*)(oln + n_p);                       // nb

    hipMemsetAsync(bres, 0, (size_t)nb * sizeof(int), stream);

    prep_kernel<<<8, 256, 0, stream>>>(Wfc, wtf);
    const int gemm_blocks = (n_w + 63) / 64;   // 1563 >= nchunks=391
    gemm_s_kernel<<<gemm_blocks, 256, 0, stream>>>(h, wtf, Wattn, esrc, edst,
                                                   z, s, bres, brec, n_w, n_e, nb);
    p2_kernel<<<nb, 256, 0, stream>>>(bres, brec, oln, n_p);
    segment_kernel<<<(n_p + 3) / 4, 256, 0, stream>>>(oln, brec, s, z, out, n_p);
}